// Round 1
// baseline (94.486 us; speedup 1.0000x reference)
//
#include <hip/hip_runtime.h>

// RASP pairwise score, N=6144 atoms, P = N(N-1)/2 pairs.
// pot tensor [K=6, T=85, T=85, D=21] fp32 = 3.64 MB (fits in per-XCD L2).
// R3: occupancy + inner-loop diet.
//  - 256-thr blocks, __launch_bounds__(256,6): VGPR<=85 -> >=24 waves/CU and
//    all 1176 tile-blocks co-resident in ONE dispatch round (no 2-round tail).
//  - sentinel coords (1e8*(i+1)) for invalid-type atoms + padding: the
//    dist<20 test subsumes type-validity and bounds checks -> inner mask is
//    just (sep>2)&(dist<20) (+ q>p on diagonal blocks only, via template).
//  - sort pre-packs key*21 into w (res<<11 | key*21): no per-pair mul.
//  - sort's serial 86-bin scan -> wave-parallel O(K^2) broadcast scan.
//  - sorted[] padded to nt*TILE by the sort kernel: pair kernel has zero
//    bounds logic.

#define T_TYPES 85
#define D_BINS 21
#define KSTRIDE (T_TYPES * T_TYPES * D_BINS)  // 151725
#define NKEYS 86                              // 85 types + 1 invalid bin
#define TILE 128
#define PAIR_THREADS 256
#define JCHUNK 64                             // TILE / (PAIR_THREADS/TILE)

// One block: zero out scalar, counting-sort by type key, write packed float4
// (xyz coords, w = res<<11 | key*21), pad to npad with far-apart sentinels.
__global__ __launch_bounds__(1024) void sort_kernel(const float* __restrict__ coords,
                                                    const int* __restrict__ res_ids,
                                                    const int* __restrict__ types,
                                                    int n, int npad,
                                                    float4* __restrict__ sorted,
                                                    float* __restrict__ out) {
    __shared__ int hist[NKEYS];
    __shared__ int offs[NKEYS];
    int tid = threadIdx.x;
    if (tid < NKEYS) hist[tid] = 0;
    if (tid == 0) *out = 0.0f;
    __syncthreads();
    for (int i = tid; i < n; i += 1024) {
        int t = types[i];
        int key = (t < 0) ? (NKEYS - 1) : t;
        atomicAdd(&hist[key], 1);
    }
    __syncthreads();
    // parallel exclusive scan over 86 bins: each owner-thread sums the bins
    // below it; hist[k] reads are wave-broadcast (same address all lanes).
    if (tid < NKEYS) {
        int s = 0;
#pragma unroll 1
        for (int k = 0; k < NKEYS; ++k) {
            int h = hist[k];
            s += (k < tid) ? h : 0;
        }
        offs[tid] = s;
    }
    __syncthreads();
    for (int i = tid; i < n; i += 1024) {
        int t = types[i];
        int inv = (t < 0);
        int key = inv ? (NKEYS - 1) : t;
        int pos = atomicAdd(&offs[key], 1);
        float4 v;
        if (inv) {
            // distinct far-apart sentinel: any pair involving this atom has
            // dist >= ~1e8 > 20 -> masked by the dist test. Finite squares.
            v.x = 1e8f * (float)(i + 1);
            v.y = 0.0f;
            v.z = 0.0f;
            v.w = __int_as_float(0);
        } else {
            v.x = coords[3 * i + 0];
            v.y = coords[3 * i + 1];
            v.z = coords[3 * i + 2];
            v.w = __int_as_float((res_ids[i] << 11) | (t * D_BINS));
        }
        sorted[pos] = v;
    }
    // pad region: also distinct sentinels (indices >= n, disjoint from the
    // invalid-atom sentinels which use original indices < n).
    for (int i = n + tid; i < npad; i += 1024) {
        float4 v;
        v.x = 1e8f * (float)(i + 1);
        v.y = 0.0f;
        v.z = 0.0f;
        v.w = __int_as_float(0);
        sorted[i] = v;
    }
}

template <bool DIAG>
__device__ __forceinline__ float tile_accum(const float4* __restrict__ jt,
                                            float4 mine, int resi, int tbase,
                                            int j0, int p, int q0,
                                            const float* __restrict__ pot) {
    float acc = 0.0f;
#pragma unroll 8
    for (int u = 0; u < JCHUNK; ++u) {
        int jj = j0 + u;
        float4 o = jt[jj];  // jj uniform per wave -> LDS broadcast, no conflict
        float dx = mine.x - o.x;
        float dy = mine.y - o.y;
        float dz = mine.z - o.z;
        float d2 = __builtin_fmaf(dx, dx, __builtin_fmaf(dy, dy, dz * dz));
        float dist = __builtin_amdgcn_sqrtf(d2) + 1e-8f;

        int packj = __float_as_int(o.w);
        int resj = packj >> 11;
        int kj21 = packj & 0x7FF;       // key_j * 21, precomputed by sort
        int sep = resi - resj;
        sep = (sep < 0) ? -sep : sep;

        int valid = (sep > 2) & (dist < 20.0f);
        if (DIAG) valid &= ((q0 + jj) > p);

        int k = sep - 1;                // sep<=2 -> invalid anyway; no low clamp
        k = (k > 5) ? 5 : k;
        int d0i = (int)dist;            // v_cvt saturates for huge sentinels
        d0i = (d0i > 19) ? 19 : d0i;
        float alpha = dist - (float)d0i;

        int idx = k * KSTRIDE + (tbase + kj21 + d0i);
        idx = valid ? idx : 0;
        float e0 = pot[idx];
        float e1 = pot[idx + 1];
        float val = __builtin_fmaf(alpha, e1 - e0, e0) - 2.7f;
        acc += valid ? val : 0.0f;
    }
    return acc;
}

__global__ __launch_bounds__(PAIR_THREADS, 6) void pair_kernel(const float4* __restrict__ sorted,
                                                               const float* __restrict__ pot,
                                                               int nt,
                                                               float* __restrict__ out) {
    __shared__ float4 jtile[TILE];
    __shared__ float wsum[PAIR_THREADS / 64];

    int b = blockIdx.x;
    // decode triangular (bi, bj), bi <= bj; row_start(r) = r*nt - r*(r-1)/2
    int bi = (int)((2.0 * nt + 1.0 -
                    sqrt((2.0 * nt + 1.0) * (2.0 * nt + 1.0) - 8.0 * (double)b)) * 0.5);
    if (bi < 0) bi = 0;
    if (bi > nt - 1) bi = nt - 1;
    while ((bi + 1) * nt - ((bi + 1) * bi) / 2 <= b) ++bi;
    while (bi * nt - (bi * (bi - 1)) / 2 > b) --bi;
    int bj = bi + (b - (bi * nt - (bi * (bi - 1)) / 2));

    int tid = threadIdx.x;
    int ilane = tid & (TILE - 1);   // 0..127: which i in the tile
    int chunk = tid >> 7;           // 0..1: which 64-wide slice of j
    int q0 = bj * TILE;
    int p = bi * TILE + ilane;

    float4 mine = sorted[p];                       // sorted[] is padded: no bounds check
    if (tid < TILE) jtile[tid] = sorted[q0 + tid];
    __syncthreads();

    int packi = __float_as_int(mine.w);
    int resi = packi >> 11;
    int tbase = (packi & 0x7FF) * T_TYPES;         // key_i*21*85 = key_i*1785
    int j0 = chunk * JCHUNK;

    float acc;
    if (bi == bj)
        acc = tile_accum<true>(jtile, mine, resi, tbase, j0, p, q0, pot);
    else
        acc = tile_accum<false>(jtile, mine, resi, tbase, j0, p, q0, pot);

    // wave (64-lane) reduce, then block reduce, then one atomic
#pragma unroll
    for (int off = 32; off > 0; off >>= 1)
        acc += __shfl_down(acc, off, 64);
    int wave = tid >> 6;
    if ((tid & 63) == 0) wsum[wave] = acc;
    __syncthreads();
    if (tid == 0) {
        float s = wsum[0] + wsum[1] + wsum[2] + wsum[3];
        atomicAdd(out, s);
    }
}

extern "C" void kernel_launch(void* const* d_in, const int* in_sizes, int n_in,
                              void* d_out, int out_size, void* d_ws, size_t ws_size,
                              hipStream_t stream) {
    const float* coords = (const float*)d_in[0];
    const int* res_ids = (const int*)d_in[1];
    const int* types   = (const int*)d_in[2];
    const float* pot   = (const float*)d_in[3];
    int n = in_sizes[1];
    float* out = (float*)d_out;

    float4* sorted = (float4*)d_ws;

    int nt = (n + TILE - 1) / TILE;
    int npad = nt * TILE;
    sort_kernel<<<1, 1024, 0, stream>>>(coords, res_ids, types, n, npad, sorted, out);

    int nblocks = nt * (nt + 1) / 2;
    pair_kernel<<<nblocks, PAIR_THREADS, 0, stream>>>(sorted, pot, nt, out);
}